// Round 1
// baseline (92.475 us; speedup 1.0000x reference)
//
#include <hip/hip_runtime.h>

// GaussianUpsampling: out[b,f,a] = sum_t softmax_t(-0.1*(t_f - c_t)^2) * hs[b,t,a]
//   c = cumsum(ds) - ds/2, t_f = f * h_mask[b,f]
// Measurement model (R4/R5): dur_us includes ~57-64us of harness poison/restore
// (256MiB ws-fill @~44us + 64MiB out-poison @~11us + input restore); the
// upsample kernel itself is ~28-35us vs an ~11us output-write floor.
// R5 -> R6:
//  - kFTile 16 -> 32 (grid 4096 -> 2048 blocks): per-block prologue (ds scan +
//    dual binary search, ~2K cyc of dependent latency) and the 4x-redundant
//    per-wave hs row reads in Phase B are amortized over 2x the output bytes.
//    Each wave now accumulates 8 frames x 4 channels (acc[8][4]).
//  - explicit hs prefetch (ping-pong n0..n3, statically indexed) overlaps the
//    L1 load latency with the 128 FMAs/iter inside each wave.
//  - launch_bounds (256,7) -> (256,5): ~102 VGPR budget for acc32+h16+n16;
//    LDS ~22 KB -> 5 blocks/CU = 20 waves/CU.

namespace {
constexpr int kB = 16;      // batch
constexpr int kT = 512;     // T_text
constexpr int kA = 256;     // adim
constexpr int kF = 4096;    // T_feats
constexpr float kDelta = 0.1f;
constexpr int kFTile = 32;  // frames per block
constexpr int kRadius = 10; // center-distance inclusion radius (frames); rel wt exp(-10)=4.5e-5
constexpr int kPad = 4;     // extra token padding each side
constexpr int kMaxK = 128;  // window cap (multiple of 4); realistic K <= ~32
constexpr int kWStride = kFTile + 4;  // [token][frame] stride: 36 floats, 16B-aligned subreads
typedef float f32x4 __attribute__((ext_vector_type(4)));  // native vec for nontemporal store
}

__global__ __launch_bounds__(256, 5) void upsample_kernel(
    const float* __restrict__ hs, const float* __restrict__ ds,
    const int* __restrict__ h_masks, const int* __restrict__ d_masks,
    float* __restrict__ out) {
  __shared__ __align__(16) float s_c[kT];
  __shared__ int s_dm[kT];
  __shared__ __align__(16) float s_w[kMaxK * kWStride];  // 18 KB
  __shared__ float s_t[kFTile];
  __shared__ float s_rsum[kFTile];
  __shared__ float s_wsum[4];

  const int id = blockIdx.x;
  const int b = id & 15;        // batch in low bits => same batch -> same XCD (id%8)
  const int f0 = (id >> 4) * kFTile;
  const int tid = threadIdx.x;
  const int wave = tid >> 6, lane = tid & 63;

  // --- fused token-center scan: thread t covers ds[2t], ds[2t+1] ---
  const float2 dsv = *reinterpret_cast<const float2*>(ds + (size_t)b * kT + 2 * tid);
  const float psum = dsv.x + dsv.y;
  float incl = psum;
#pragma unroll
  for (int off = 1; off < 64; off <<= 1) {
    float u = __shfl_up(incl, off, 64);
    if (lane >= off) incl += u;
  }
  if (lane == 63) s_wsum[wave] = incl;

  for (int j = tid; j < kT; j += 256) s_dm[j] = d_masks[(size_t)b * kT + j];
  if (tid < kFTile) {
    const int f = f0 + tid;
    s_t[tid] = h_masks[(size_t)b * kF + f] ? (float)f : 0.0f;
  }
  __syncthreads();

  float basesum = 0.0f;
#pragma unroll
  for (int w = 0; w < 4; ++w)
    if (w < wave) basesum += s_wsum[w];
  const float excl = basesum + incl - psum;
  s_c[2 * tid]     = excl + 0.5f * dsv.x;
  s_c[2 * tid + 1] = excl + dsv.x + 0.5f * dsv.y;
  __syncthreads();

  // --- window selection (uniform across block) ---
  float tmin = s_t[0], tmax = s_t[0];
#pragma unroll
  for (int i = 1; i < kFTile; ++i) {
    tmin = fminf(tmin, s_t[i]);
    tmax = fmaxf(tmax, s_t[i]);
  }
  const float lo = tmin - (float)kRadius;
  const float hi = tmax + (float)kRadius;
  // fused dual binary search: probes are independent -> latencies overlap
  int alo = 0, elo = kT;   // lower_bound: first j with c[j] >= lo
  int ahi = 0, ehi = kT;   // upper_bound: first j with c[j] > hi
#pragma unroll
  for (int it = 0; it < 9; ++it) {  // ceil(log2(512)) = 9 halvings each
    const int m1 = (alo + elo) >> 1;
    const int m2 = (ahi + ehi) >> 1;
    const float c1 = s_c[m1];
    const float c2 = s_c[m2];
    if (alo < elo) { if (c1 < lo) alo = m1 + 1; else elo = m1; }
    if (ahi < ehi) { if (c2 <= hi) ahi = m2 + 1; else ehi = m2; }
  }
  int jlo = max(0, alo - kPad);
  int jhi = min(kT, ahi + kPad);
  int K = jhi - jlo;
  if (K > kMaxK) {  // keep the central (highest-weight) tokens
    jlo += (K - kMaxK) >> 1;
    jhi = jlo + kMaxK;
    K = kMaxK;
  }
  {  // pad K to a multiple of 4 with real in-range tokens (weights ~0 anyway)
    const int ext = (4 - (K & 3)) & 3;
    if (jhi + ext <= kT) jhi += ext; else jlo -= ext;
    K += ext;
  }

  // --- Phase A: windowed softmax weights into LDS [token][frame] ---
  // 32 frame-groups x 8 lanes; addr = jj*36 + g -> exactly 2 lanes/bank (free)
  const int g = tid >> 3;   // frame group 0..31
  const int l = tid & 7;    // lane within group
  const float tf = s_t[g];
  float m = -1e38f;
  for (int jj = l; jj < K; jj += 8) {
    const int j = jlo + jj;
    const float d = tf - s_c[j];
    float e = -kDelta * d * d;
    if (!s_dm[j]) e = -1e30f;
    s_w[jj * kWStride + g] = e;
    m = fmaxf(m, e);
  }
#pragma unroll
  for (int off = 4; off >= 1; off >>= 1) m = fmaxf(m, __shfl_xor(m, off, 8));
  float ssum = 0.0f;
  for (int jj = l; jj < K; jj += 8) {
    const float w = __expf(s_w[jj * kWStride + g] - m);
    s_w[jj * kWStride + g] = w;
    ssum += w;
  }
#pragma unroll
  for (int off = 4; off >= 1; off >>= 1) ssum += __shfl_xor(ssum, off, 8);
  if (l == 0) s_rsum[g] = 1.0f / ssum;
  __syncthreads();

  // --- Phase B: windowed einsum; wave q owns frames 8q..8q+7, all 256 ch ---
  const int q = tid >> 6;          // frame octet (wave-uniform) -> LDS broadcast
  const int ch = (tid & 63) << 2;  // float4 channel slice, coalesced
  const float* hp = hs + ((size_t)b * kT + jlo) * kA + ch;
  float acc[8][4];
#pragma unroll
  for (int i = 0; i < 8; ++i)
#pragma unroll
    for (int k = 0; k < 4; ++k) acc[i][k] = 0.0f;

  // preload first token quad (K >= 4 always)
  f32x4 h0 = *reinterpret_cast<const f32x4*>(hp);
  f32x4 h1 = *reinterpret_cast<const f32x4*>(hp + kA);
  f32x4 h2 = *reinterpret_cast<const f32x4*>(hp + 2 * kA);
  f32x4 h3 = *reinterpret_cast<const f32x4*>(hp + 3 * kA);

  for (int jj = 0; jj < K; jj += 4) {
    // prefetch next quad (clamped to a safe re-read on the last iter)
    const float* hpn = hp + ((jj + 4 < K) ? 4 * kA : 0);
    const f32x4 n0 = *reinterpret_cast<const f32x4*>(hpn);
    const f32x4 n1 = *reinterpret_cast<const f32x4*>(hpn + kA);
    const f32x4 n2 = *reinterpret_cast<const f32x4*>(hpn + 2 * kA);
    const f32x4 n3 = *reinterpret_cast<const f32x4*>(hpn + 3 * kA);

    const float* wb = s_w + jj * kWStride + 8 * q;
#pragma unroll
    for (int mm = 0; mm < 4; ++mm) {  // token within quad (compile-time)
      const f32x4 wlo = *reinterpret_cast<const f32x4*>(wb + mm * kWStride);
      const f32x4 whi = *reinterpret_cast<const f32x4*>(wb + mm * kWStride + 4);
      const f32x4 hm = (mm == 0) ? h0 : (mm == 1) ? h1 : (mm == 2) ? h2 : h3;
      const float hf[4] = {hm.x, hm.y, hm.z, hm.w};
      const float wf[8] = {wlo.x, wlo.y, wlo.z, wlo.w, whi.x, whi.y, whi.z, whi.w};
#pragma unroll
      for (int i = 0; i < 8; ++i)
#pragma unroll
        for (int k = 0; k < 4; ++k) acc[i][k] += wf[i] * hf[k];
    }
    h0 = n0; h1 = n1; h2 = n2; h3 = n3;
    hp = hpn;
  }

  float* ob = out + ((size_t)b * kF + (size_t)(f0 + 8 * q)) * kA + ch;
#pragma unroll
  for (int i = 0; i < 8; ++i) {
    const float r = s_rsum[8 * q + i];
    f32x4 o;
    o.x = acc[i][0] * r; o.y = acc[i][1] * r;
    o.z = acc[i][2] * r; o.w = acc[i][3] * r;
    __builtin_nontemporal_store(o, reinterpret_cast<f32x4*>(ob + (size_t)i * kA));
  }
}

extern "C" void kernel_launch(void* const* d_in, const int* in_sizes, int n_in,
                              void* d_out, int out_size, void* d_ws, size_t ws_size,
                              hipStream_t stream) {
  const float* hs = (const float*)d_in[0];   // (16, 512, 256) fp32
  const float* ds = (const float*)d_in[1];   // (16, 512) fp32
  const int* h_masks = (const int*)d_in[2];  // (16, 4096) bool -> int32
  const int* d_masks = (const int*)d_in[3];  // (16, 512) bool -> int32
  float* out = (float*)d_out;                // (16, 4096, 256) fp32

  upsample_kernel<<<kB * (kF / kFTile), 256, 0, stream>>>(hs, ds, h_masks, d_masks, out);
}

// Round 2
// 89.308 us; speedup vs baseline: 1.0355x; 1.0355x over previous
//
#include <hip/hip_runtime.h>

// GaussianUpsampling: out[b,f,a] = sum_t softmax_t(-0.1*(t_f - c_t)^2) * hs[b,t,a]
//   c = cumsum(ds) - ds/2, t_f = f * h_mask[b,f]
// Measurement model (R6 post-mortem): dur_us ~92us includes ~78us of harness
// poison/restore + graph gaps; the upsample kernel itself is ~12-15us against
// an ~11us output-write floor (64 MiB @ ~6.1 TB/s fill-rate). R5 (4096 blocks,
// 7/CU) and R6 (2048 blocks, 5/CU, prefetch) were identical within noise ->
// prologue latency and hs-read redundancy are fully latency-hidden; the kernel
// is STORE-bound.
// R6 -> R7: drop __builtin_nontemporal_store -> plain f32x4 stores. The rocclr
// fill hits 6.15 TB/s with regular stores into this same buffer; NT stores
// bypass L2/L3, must probe the freshly-poisoned dirty lines, and forgo the
// 256 MiB L3 as a write-drain buffer (out = 64 MiB fits). Only store-path knob
// left. Neutral result here => kernel at store floor => roofline.

namespace {
constexpr int kB = 16;      // batch
constexpr int kT = 512;     // T_text
constexpr int kA = 256;     // adim
constexpr int kF = 4096;    // T_feats
constexpr float kDelta = 0.1f;
constexpr int kFTile = 32;  // frames per block
constexpr int kRadius = 10; // center-distance inclusion radius (frames); rel wt exp(-10)=4.5e-5
constexpr int kPad = 4;     // extra token padding each side
constexpr int kMaxK = 128;  // window cap (multiple of 4); realistic K <= ~32
constexpr int kWStride = kFTile + 4;  // [token][frame] stride: 36 floats, 16B-aligned subreads
typedef float f32x4 __attribute__((ext_vector_type(4)));
}

__global__ __launch_bounds__(256, 5) void upsample_kernel(
    const float* __restrict__ hs, const float* __restrict__ ds,
    const int* __restrict__ h_masks, const int* __restrict__ d_masks,
    float* __restrict__ out) {
  __shared__ __align__(16) float s_c[kT];
  __shared__ int s_dm[kT];
  __shared__ __align__(16) float s_w[kMaxK * kWStride];  // 18 KB
  __shared__ float s_t[kFTile];
  __shared__ float s_rsum[kFTile];
  __shared__ float s_wsum[4];

  const int id = blockIdx.x;
  const int b = id & 15;        // batch in low bits => same batch -> same XCD (id%8)
  const int f0 = (id >> 4) * kFTile;
  const int tid = threadIdx.x;
  const int wave = tid >> 6, lane = tid & 63;

  // --- fused token-center scan: thread t covers ds[2t], ds[2t+1] ---
  const float2 dsv = *reinterpret_cast<const float2*>(ds + (size_t)b * kT + 2 * tid);
  const float psum = dsv.x + dsv.y;
  float incl = psum;
#pragma unroll
  for (int off = 1; off < 64; off <<= 1) {
    float u = __shfl_up(incl, off, 64);
    if (lane >= off) incl += u;
  }
  if (lane == 63) s_wsum[wave] = incl;

  for (int j = tid; j < kT; j += 256) s_dm[j] = d_masks[(size_t)b * kT + j];
  if (tid < kFTile) {
    const int f = f0 + tid;
    s_t[tid] = h_masks[(size_t)b * kF + f] ? (float)f : 0.0f;
  }
  __syncthreads();

  float basesum = 0.0f;
#pragma unroll
  for (int w = 0; w < 4; ++w)
    if (w < wave) basesum += s_wsum[w];
  const float excl = basesum + incl - psum;
  s_c[2 * tid]     = excl + 0.5f * dsv.x;
  s_c[2 * tid + 1] = excl + dsv.x + 0.5f * dsv.y;
  __syncthreads();

  // --- window selection (uniform across block) ---
  float tmin = s_t[0], tmax = s_t[0];
#pragma unroll
  for (int i = 1; i < kFTile; ++i) {
    tmin = fminf(tmin, s_t[i]);
    tmax = fmaxf(tmax, s_t[i]);
  }
  const float lo = tmin - (float)kRadius;
  const float hi = tmax + (float)kRadius;
  // fused dual binary search: probes are independent -> latencies overlap
  int alo = 0, elo = kT;   // lower_bound: first j with c[j] >= lo
  int ahi = 0, ehi = kT;   // upper_bound: first j with c[j] > hi
#pragma unroll
  for (int it = 0; it < 9; ++it) {  // ceil(log2(512)) = 9 halvings each
    const int m1 = (alo + elo) >> 1;
    const int m2 = (ahi + ehi) >> 1;
    const float c1 = s_c[m1];
    const float c2 = s_c[m2];
    if (alo < elo) { if (c1 < lo) alo = m1 + 1; else elo = m1; }
    if (ahi < ehi) { if (c2 <= hi) ahi = m2 + 1; else ehi = m2; }
  }
  int jlo = max(0, alo - kPad);
  int jhi = min(kT, ahi + kPad);
  int K = jhi - jlo;
  if (K > kMaxK) {  // keep the central (highest-weight) tokens
    jlo += (K - kMaxK) >> 1;
    jhi = jlo + kMaxK;
    K = kMaxK;
  }
  {  // pad K to a multiple of 4 with real in-range tokens (weights ~0 anyway)
    const int ext = (4 - (K & 3)) & 3;
    if (jhi + ext <= kT) jhi += ext; else jlo -= ext;
    K += ext;
  }

  // --- Phase A: windowed softmax weights into LDS [token][frame] ---
  // 32 frame-groups x 8 lanes; addr = jj*36 + g -> exactly 2 lanes/bank (free)
  const int g = tid >> 3;   // frame group 0..31
  const int l = tid & 7;    // lane within group
  const float tf = s_t[g];
  float m = -1e38f;
  for (int jj = l; jj < K; jj += 8) {
    const int j = jlo + jj;
    const float d = tf - s_c[j];
    float e = -kDelta * d * d;
    if (!s_dm[j]) e = -1e30f;
    s_w[jj * kWStride + g] = e;
    m = fmaxf(m, e);
  }
#pragma unroll
  for (int off = 4; off >= 1; off >>= 1) m = fmaxf(m, __shfl_xor(m, off, 8));
  float ssum = 0.0f;
  for (int jj = l; jj < K; jj += 8) {
    const float w = __expf(s_w[jj * kWStride + g] - m);
    s_w[jj * kWStride + g] = w;
    ssum += w;
  }
#pragma unroll
  for (int off = 4; off >= 1; off >>= 1) ssum += __shfl_xor(ssum, off, 8);
  if (l == 0) s_rsum[g] = 1.0f / ssum;
  __syncthreads();

  // --- Phase B: windowed einsum; wave q owns frames 8q..8q+7, all 256 ch ---
  const int q = tid >> 6;          // frame octet (wave-uniform) -> LDS broadcast
  const int ch = (tid & 63) << 2;  // float4 channel slice, coalesced
  const float* hp = hs + ((size_t)b * kT + jlo) * kA + ch;
  float acc[8][4];
#pragma unroll
  for (int i = 0; i < 8; ++i)
#pragma unroll
    for (int k = 0; k < 4; ++k) acc[i][k] = 0.0f;

  // preload first token quad (K >= 4 always)
  f32x4 h0 = *reinterpret_cast<const f32x4*>(hp);
  f32x4 h1 = *reinterpret_cast<const f32x4*>(hp + kA);
  f32x4 h2 = *reinterpret_cast<const f32x4*>(hp + 2 * kA);
  f32x4 h3 = *reinterpret_cast<const f32x4*>(hp + 3 * kA);

  for (int jj = 0; jj < K; jj += 4) {
    // prefetch next quad (clamped to a safe re-read on the last iter)
    const float* hpn = hp + ((jj + 4 < K) ? 4 * kA : 0);
    const f32x4 n0 = *reinterpret_cast<const f32x4*>(hpn);
    const f32x4 n1 = *reinterpret_cast<const f32x4*>(hpn + kA);
    const f32x4 n2 = *reinterpret_cast<const f32x4*>(hpn + 2 * kA);
    const f32x4 n3 = *reinterpret_cast<const f32x4*>(hpn + 3 * kA);

    const float* wb = s_w + jj * kWStride + 8 * q;
#pragma unroll
    for (int mm = 0; mm < 4; ++mm) {  // token within quad (compile-time)
      const f32x4 wlo = *reinterpret_cast<const f32x4*>(wb + mm * kWStride);
      const f32x4 whi = *reinterpret_cast<const f32x4*>(wb + mm * kWStride + 4);
      const f32x4 hm = (mm == 0) ? h0 : (mm == 1) ? h1 : (mm == 2) ? h2 : h3;
      const float hf[4] = {hm.x, hm.y, hm.z, hm.w};
      const float wf[8] = {wlo.x, wlo.y, wlo.z, wlo.w, whi.x, whi.y, whi.z, whi.w};
#pragma unroll
      for (int i = 0; i < 8; ++i)
#pragma unroll
        for (int k = 0; k < 4; ++k) acc[i][k] += wf[i] * hf[k];
    }
    h0 = n0; h1 = n1; h2 = n2; h3 = n3;
    hp = hpn;
  }

  float* ob = out + ((size_t)b * kF + (size_t)(f0 + 8 * q)) * kA + ch;
#pragma unroll
  for (int i = 0; i < 8; ++i) {
    const float r = s_rsum[8 * q + i];
    f32x4 o;
    o.x = acc[i][0] * r; o.y = acc[i][1] * r;
    o.z = acc[i][2] * r; o.w = acc[i][3] * r;
    *reinterpret_cast<f32x4*>(ob + (size_t)i * kA) = o;  // R7: plain store (was NT)
  }
}

extern "C" void kernel_launch(void* const* d_in, const int* in_sizes, int n_in,
                              void* d_out, int out_size, void* d_ws, size_t ws_size,
                              hipStream_t stream) {
  const float* hs = (const float*)d_in[0];   // (16, 512, 256) fp32
  const float* ds = (const float*)d_in[1];   // (16, 512) fp32
  const int* h_masks = (const int*)d_in[2];  // (16, 4096) bool -> int32
  const int* d_masks = (const int*)d_in[3];  // (16, 512) bool -> int32
  float* out = (float*)d_out;                // (16, 4096, 256) fp32

  upsample_kernel<<<kB * (kF / kFTile), 256, 0, stream>>>(hs, ds, h_masks, d_masks, out);
}